// Round 3
// baseline (125.262 us; speedup 1.0000x reference)
//
#include <hip/hip_runtime.h>

#define BATCH 128
#define M 259
#define D 512
#define T 256
#define NM (BATCH * M)          // 33152
#define OUTHALF (BATCH * T * D)

typedef __bf16 bf16;
typedef __bf16 bf16x4 __attribute__((ext_vector_type(4)));
typedef __bf16 bf16x8 __attribute__((ext_vector_type(8)));
typedef float f32x4 __attribute__((ext_vector_type(4)));

// ws float layout: wcol[NM] | wrow[NM]

// ---------------- Kernel 0: zero the accumulators ----------------
__global__ void k_zero(float4* __restrict__ ws4) {
    int i = blockIdx.x * 256 + threadIdx.x;
    if (i < (2 * NM + 3) / 4) ws4[i] = make_float4(0.f, 0.f, 0.f, 0.f);
}

// ---------------- Kernel 1: bf16 MFMA pairwise + fused norms + sums --------
#define BT 96
#define BK 64
#define NTL 3   // tiles per dim (3*96 = 288 >= 259)

__launch_bounds__(256)
__global__ void k_pairs(const float* __restrict__ x1, const float* __restrict__ x2,
                        float* __restrict__ ws) {
    __shared__ __align__(16) bf16 As[BT * BK];
    __shared__ __align__(16) bf16 Bs[BT * BK];
    __shared__ float na_s[BT];
    __shared__ float nb_s[BT];

    // XCD-aware bijective swizzle: 1152 blocks = 8 * 144
    int s   = blockIdx.x;
    int bid = (s & 7) * 144 + (s >> 3);
    int b   = bid / 9;
    int ti  = (bid % 9) / 3;
    int tj  = bid % 3;
    int i0  = ti * BT, j0 = tj * BT;

    int t    = threadIdx.x;
    int lane = t & 63;
    int w    = t >> 6;
    int wm   = w >> 1, wn = w & 1;
    int iw   = i0 + wm * 48;
    int jw   = j0 + wn * 48;

    const float* Ab = x1 + (size_t)b * M * D;
    const float* Bb = x2 + (size_t)b * M * D;

    // staging: 6 passes of 16 rows x 64 cols, 1 float4/thread/pass
    const float* pa[6];
    const float* pb[6];
    int c4 = (t & 15) * 4;
#pragma unroll
    for (int p = 0; p < 6; ++p) {
        int ra = min(i0 + p * 16 + (t >> 4), M - 1);
        int rb = min(j0 + p * 16 + (t >> 4), M - 1);
        pa[p] = Ab + (size_t)ra * D + c4;
        pb[p] = Bb + (size_t)rb * D + c4;
    }
    int wslot   = (t & 15) >> 1;
    int wwithin = (t & 1) * 4;
    int wr_off[6];
#pragma unroll
    for (int p = 0; p < 6; ++p) {
        int row = p * 16 + (t >> 4);
        wr_off[p] = row * BK + ((wslot ^ (row & 7)) << 3) + wwithin;
    }

    // fragment read offsets, swizzle-matched
    int a_off[3][2], b_off[3][2];
#pragma unroll
    for (int fm = 0; fm < 3; ++fm) {
        int rowa = wm * 48 + fm * 16 + (lane & 15);
        int rowb = wn * 48 + fm * 16 + (lane & 15);
#pragma unroll
        for (int kk = 0; kk < 2; ++kk) {
            int slot = kk * 4 + (lane >> 4);
            a_off[fm][kk] = rowa * BK + ((slot ^ (rowa & 7)) << 3);
            b_off[fm][kk] = rowb * BK + ((slot ^ (rowb & 7)) << 3);
        }
    }

    f32x4 acc[3][3];
#pragma unroll
    for (int fm = 0; fm < 3; ++fm)
#pragma unroll
        for (int fn = 0; fn < 3; ++fn) acc[fm][fn] = (f32x4)0.f;

    float sa[6], sb[6];
#pragma unroll
    for (int p = 0; p < 6; ++p) { sa[p] = 0.f; sb[p] = 0.f; }

    // T14 rotation: prologue loads for k0=0
    float4 va[6], vb[6];
#pragma unroll
    for (int p = 0; p < 6; ++p) {
        va[p] = *(const float4*)(pa[p]);
        vb[p] = *(const float4*)(pb[p]);
    }

    for (int k0 = 0; k0 < D; k0 += BK) {
        // convert + norm-accumulate (uses regs loaded last iter / prologue)
        bf16x4 ca[6], cb[6];
#pragma unroll
        for (int p = 0; p < 6; ++p) {
            sa[p] += va[p].x * va[p].x + va[p].y * va[p].y
                   + va[p].z * va[p].z + va[p].w * va[p].w;
            sb[p] += vb[p].x * vb[p].x + vb[p].y * vb[p].y
                   + vb[p].z * vb[p].z + vb[p].w * vb[p].w;
            ca[p] = { (bf16)va[p].x, (bf16)va[p].y, (bf16)va[p].z, (bf16)va[p].w };
            cb[p] = { (bf16)vb[p].x, (bf16)vb[p].y, (bf16)vb[p].z, (bf16)vb[p].w };
        }
        __syncthreads();
#pragma unroll
        for (int p = 0; p < 6; ++p) {
            *(bf16x4*)&As[wr_off[p]] = ca[p];
            *(bf16x4*)&Bs[wr_off[p]] = cb[p];
        }
        // issue next-tile loads; latency hides under MFMA phase below
        if (k0 + BK < D) {
#pragma unroll
            for (int p = 0; p < 6; ++p) {
                va[p] = *(const float4*)(pa[p] + k0 + BK);
                vb[p] = *(const float4*)(pb[p] + k0 + BK);
            }
        }
        __syncthreads();
#pragma unroll
        for (int kk = 0; kk < 2; ++kk) {
            bf16x8 af[3], bfr[3];
#pragma unroll
            for (int fm = 0; fm < 3; ++fm) af[fm]  = *(const bf16x8*)&As[a_off[fm][kk]];
#pragma unroll
            for (int fn = 0; fn < 3; ++fn) bfr[fn] = *(const bf16x8*)&Bs[b_off[fn][kk]];
#pragma unroll
            for (int fm = 0; fm < 3; ++fm)
#pragma unroll
                for (int fn = 0; fn < 3; ++fn)
                    acc[fm][fn] = __builtin_amdgcn_mfma_f32_16x16x32_bf16(
                        af[fm], bfr[fn], acc[fm][fn], 0, 0, 0);
        }
    }

    // norm reduce across the 16 lanes sharing a staging row -> LDS
#pragma unroll
    for (int p = 0; p < 6; ++p) {
        float v1 = sa[p], v2 = sb[p];
        v1 += __shfl_xor(v1, 1); v1 += __shfl_xor(v1, 2);
        v1 += __shfl_xor(v1, 4); v1 += __shfl_xor(v1, 8);
        v2 += __shfl_xor(v2, 1); v2 += __shfl_xor(v2, 2);
        v2 += __shfl_xor(v2, 4); v2 += __shfl_xor(v2, 8);
        if ((t & 15) == 0) {
            na_s[p * 16 + (t >> 4)] = v1;
            nb_s[p * 16 + (t >> 4)] = v2;
        }
    }
    __syncthreads();

    // epilogue: A_ij = 1/(1+dist), masked; row/col partial sums
    int b_off_w = b * M;
    float na_[3][4], nb_[3];
#pragma unroll
    for (int fm = 0; fm < 3; ++fm)
#pragma unroll
        for (int r = 0; r < 4; ++r)
            na_[fm][r] = na_s[wm * 48 + fm * 16 + (lane >> 4) * 4 + r];
#pragma unroll
    for (int fn = 0; fn < 3; ++fn)
        nb_[fn] = nb_s[wn * 48 + fn * 16 + (lane & 15)];

    float rs[3][4];
    float cs[3];
#pragma unroll
    for (int fm = 0; fm < 3; ++fm)
#pragma unroll
        for (int r = 0; r < 4; ++r) rs[fm][r] = 0.f;
#pragma unroll
    for (int fn = 0; fn < 3; ++fn) cs[fn] = 0.f;

#pragma unroll
    for (int fm = 0; fm < 3; ++fm) {
#pragma unroll
        for (int fn = 0; fn < 3; ++fn) {
#pragma unroll
            for (int r = 0; r < 4; ++r) {
                int i = iw + fm * 16 + (lane >> 4) * 4 + r;
                int j = jw + fn * 16 + (lane & 15);
                float av = 0.f;
                if (i < M && j < M) {
                    float sq   = na_[fm][r] + nb_[fn] - 2.f * acc[fm][fn][r];
                    float dist = sqrtf(fmaxf(sq, 0.f));
                    av = 1.f / (1.f + dist);
                }
                rs[fm][r] += av;
                cs[fn]    += av;
            }
        }
    }

#pragma unroll
    for (int fm = 0; fm < 3; ++fm)
#pragma unroll
        for (int r = 0; r < 4; ++r) {
            float v = rs[fm][r];
            v += __shfl_xor(v, 1); v += __shfl_xor(v, 2);
            v += __shfl_xor(v, 4); v += __shfl_xor(v, 8);
            int i = iw + fm * 16 + (lane >> 4) * 4 + r;
            if ((lane & 15) == 0 && i < M) atomicAdd(&ws[NM + b_off_w + i], v);  // wrow
        }
#pragma unroll
    for (int fn = 0; fn < 3; ++fn) {
        float v = cs[fn];
        v += __shfl_xor(v, 16); v += __shfl_xor(v, 32);
        int j = jw + fn * 16 + (lane & 15);
        if ((lane >> 4) == 0 && j < M) atomicAdd(&ws[b_off_w + j], v);           // wcol
    }
}

// ---------------- Kernel 2: sliding-window weighted sum (float4) -----------
__global__ void k_out(const float* __restrict__ x1, const float* __restrict__ x2,
                      const float* __restrict__ ws, float* __restrict__ out) {
    int bid   = blockIdx.x;
    int which = bid & 1;
    int tc    = (bid >> 1) & 7;  // 8 chunks of 32 rows
    int b     = bid >> 4;
    int d4    = threadIdx.x << 2;  // 128 threads cover 512 floats
    const float* src  = which ? x2 : x1;
    const float* wgt  = ws + (which ? NM : 0) + b * M;
    const float* rows = src + (size_t)b * M * D + d4;
    float* o = out + (size_t)which * OUTHALF + ((size_t)b * T + tc * 32) * D + d4;
    int t0 = tc * 32;
    float4 v0 = *(const float4*)(rows + (size_t)(t0 + 0) * D);
    float4 v1 = *(const float4*)(rows + (size_t)(t0 + 1) * D);
    float4 v2 = *(const float4*)(rows + (size_t)(t0 + 2) * D);
    float s0 = wgt[t0 + 0], s1 = wgt[t0 + 1], s2 = wgt[t0 + 2];
#pragma unroll 4
    for (int tt = 0; tt < 32; ++tt) {
        float4 v3 = *(const float4*)(rows + (size_t)(t0 + tt + 3) * D);
        float s3  = wgt[t0 + tt + 3];
        float4 r;
        r.x = s0 * v0.x + s1 * v1.x + s2 * v2.x + s3 * v3.x;
        r.y = s0 * v0.y + s1 * v1.y + s2 * v2.y + s3 * v3.y;
        r.z = s0 * v0.z + s1 * v1.z + s2 * v2.z + s3 * v3.z;
        r.w = s0 * v0.w + s1 * v1.w + s2 * v2.w + s3 * v3.w;
        *(float4*)(o + (size_t)tt * D) = r;
        v0 = v1; v1 = v2; v2 = v3;
        s0 = s1; s1 = s2; s2 = s3;
    }
}

extern "C" void kernel_launch(void* const* d_in, const int* in_sizes, int n_in,
                              void* d_out, int out_size, void* d_ws, size_t ws_size,
                              hipStream_t stream) {
    const float* x1 = (const float*)d_in[0];
    const float* x2 = (const float*)d_in[1];
    float* out = (float*)d_out;
    float* ws  = (float*)d_ws;

    k_zero<<<(2 * NM / 4 + 255) / 256, 256, 0, stream>>>((float4*)ws);   // 65 blocks
    k_pairs<<<BATCH * NTL * NTL, 256, 0, stream>>>(x1, x2, ws);          // 1152 blocks
    k_out<<<BATCH * 16, 128, 0, stream>>>(x1, x2, ws, out);              // 2048 blocks
}